// Round 12
// baseline (129.375 us; speedup 1.0000x reference)
//
#include <hip/hip_runtime.h>
#include <hip/hip_bf16.h>

typedef __attribute__((ext_vector_type(8))) unsigned short ushort8;
typedef __attribute__((ext_vector_type(4))) unsigned short ushort4v;
typedef __attribute__((ext_vector_type(8))) short short8v;
typedef __attribute__((ext_vector_type(4))) float f32x4;

__device__ __forceinline__ float bf2f(unsigned short u){
  union { unsigned int i; float f; } x; x.i = ((unsigned int)u) << 16; return x.f;
}
__device__ __forceinline__ unsigned short f2bf(float f){
  __hip_bfloat16 h = __float2bfloat16(f);
  return *reinterpret_cast<unsigned short*>(&h);
}

// XCD-affine block decode: p%8 = XCD slot; each XCD owns batches {xcd, xcd+8}.
__device__ __forceinline__ void sw_decode(int p, int NB, int& b, int& off){
  int xcd = p & 7, q = p >> 3;
  int hi = (q >= NB) ? 1 : 0;
  b = xcd + (hi << 3);
  off = q - (hi ? NB : 0);
}

// ---- prep: col8/val8 (deg padded to 8) via binary searches; dvec; zero g ----
__global__ void prep_k(const int* __restrict__ row, const int* __restrict__ colx,
                       const float* __restrict__ vals, int nnz,
                       int* __restrict__ col8, float* __restrict__ val8,
                       float* __restrict__ dvec, float* __restrict__ g, int V, int GN){
  int v = blockIdx.x*256 + threadIdx.x;
  if (v < GN) g[v] = 0.f;
  if (v >= V) return;
  int lo = 0, hi = nnz;
  while (lo < hi){ int m = (lo+hi)>>1; if (row[m] < v) lo = m+1; else hi = m; }
  int e0 = lo;
  int lo2 = e0; hi = nnz;
  while (lo2 < hi){ int m = (lo2+hi)>>1; if (row[m] < v+1) lo2 = m+1; else hi = m; }
  int e1 = lo2;
  float s = 0.f;
  #pragma unroll
  for (int i=0;i<8;i++){
    int e = e0 + i;
    int c  = (e < e1) ? colx[e] : 0;
    float wv = (e < e1) ? vals[e] : 0.f;
    col8[v*8+i] = c; val8[v*8+i] = wv; s += wv;
  }
  dvec[v] = s;
}

__device__ __forceinline__ void load_nbr(const int* __restrict__ col8,
    const float* __restrict__ val8, int v, int* cols, float* vv){
  int4 ca = *reinterpret_cast<const int4*>(col8 + v*8);
  int4 cb = *reinterpret_cast<const int4*>(col8 + v*8 + 4);
  float4 va = *reinterpret_cast<const float4*>(val8 + v*8);
  float4 vb = *reinterpret_cast<const float4*>(val8 + v*8 + 4);
  cols[0]=ca.x; cols[1]=ca.y; cols[2]=ca.z; cols[3]=ca.w;
  cols[4]=cb.x; cols[5]=cb.y; cols[6]=cb.z;
  vv[0]=va.x; vv[1]=va.y; vv[2]=va.z; vv[3]=va.w;
  vv[4]=vb.x; vv[5]=vb.y; vv[6]=vb.z;
}

// ---- layer1 (XCD-affine): h1[b*V+v] = relu(spmm(x)@W1^T + d*b1) ----
__global__ void spmm_lin1_k(const float* __restrict__ x, const int* __restrict__ col8,
    const float* __restrict__ val8, const float* __restrict__ d,
    const float* __restrict__ W1, const float* __restrict__ b1,
    unsigned short* __restrict__ out, int V, int NB){
  __shared__ float sW[192];
  __shared__ float sB[64];
  int tid = threadIdx.x;
  if (tid < 192) sW[tid] = W1[tid];
  if (tid < 64)  sB[tid] = b1[tid];
  __syncthreads();
  int b, off; sw_decode(blockIdx.x, NB, b, off);
  int v = off*256 + tid;
  if (v >= V) return;
  const float* xb = x + (size_t)b*V*3;
  int   cs[7]; float ws[7];
  load_nbr(col8, val8, v, cs, ws);
  float s0=0.f, s1=0.f, s2=0.f;
  #pragma unroll
  for (int i=0;i<7;i++){
    const float* xr = xb + (size_t)cs[i]*3;
    s0 += ws[i]*xr[0]; s1 += ws[i]*xr[1]; s2 += ws[i]*xr[2];
  }
  float dv = d[v];
  unsigned short* orow = out + ((size_t)b*V + v)*64;
  #pragma unroll
  for (int cg=0; cg<8; ++cg){
    ushort8 o;
    #pragma unroll
    for (int k=0;k<8;k++){
      int c = cg*8 + k;
      float acc = dv*sB[c] + s0*sW[c*3] + s1*sW[c*3+1] + s2*sW[c*3+2];
      o[k] = f2bf(fmaxf(acc, 0.f));
    }
    *reinterpret_cast<ushort8*>(orow + cg*8) = o;
  }
}

// ---- SPMM deg-7, 16ch/thread (4 threads/vertex), XCD-affine, 14 outstanding gathers ----
__global__ __launch_bounds__(256) void spmm16s_k(const unsigned short* __restrict__ in,
    unsigned short* __restrict__ out, const int* __restrict__ col8,
    const float* __restrict__ val8, int V, int NB){
  int b, off; sw_decode(blockIdx.x, NB, b, off);
  int j = off*256 + (int)threadIdx.x;
  if (j >= V*4) return;
  int cg = j & 3; int v = j >> 2;
  const unsigned short* base = in + (size_t)b*V*64 + cg*16;
  int cols[7]; float vv[7];
  load_nbr(col8, val8, v, cols, vv);
  ushort8 ga[7], gb[7];
  #pragma unroll
  for (int i=0;i<7;i++){
    const unsigned short* p = base + (size_t)cols[i]*64;
    ga[i] = *reinterpret_cast<const ushort8*>(p);
    gb[i] = *reinterpret_cast<const ushort8*>(p + 8);
  }
  float acc[16];
  #pragma unroll
  for (int k=0;k<16;k++) acc[k] = 0.f;
  #pragma unroll
  for (int i=0;i<7;i++){
    float s = vv[i];
    #pragma unroll
    for (int k=0;k<8;k++){ acc[k] += s*bf2f(ga[i][k]); acc[8+k] += s*bf2f(gb[i][k]); }
  }
  ushort8 oa, ob;
  #pragma unroll
  for (int k=0;k<8;k++){ oa[k] = f2bf(acc[k]); ob[k] = f2bf(acc[8+k]); }
  unsigned short* op = out + ((size_t)b*V + v)*64 + cg*16;
  *reinterpret_cast<ushort8*>(op)     = oa;
  *reinterpret_cast<ushort8*>(op + 8) = ob;
}

// ---- MFMA dense linear, persistent weights, 4 row-groups/wave (256-vertex tiles) ----
template<int K, int N, bool RELU>
__global__ __launch_bounds__(256) void lin_mfma_k(const unsigned short* __restrict__ in,
    const float* __restrict__ W, const float* __restrict__ bias,
    unsigned short* __restrict__ out, const float* __restrict__ dvec, int V,
    int NBLK, int NT){
  constexpr int KP = K + 8;
  constexpr int NF = N / 16;
  constexpr int KS = K / 32;
  __shared__ unsigned short sW[N * KP];
  __shared__ float sB[N];
  int tid = threadIdx.x;
  for (int i = tid*4; i < N*K; i += 1024){
    const float4 wv = *reinterpret_cast<const float4*>(W + i);
    int n = i / K, k = i - n*K;
    unsigned short* dst = &sW[n*KP + k];
    dst[0] = f2bf(wv.x); dst[1] = f2bf(wv.y); dst[2] = f2bf(wv.z); dst[3] = f2bf(wv.w);
  }
  if (tid < N) sB[tid] = bias[tid];
  __syncthreads();

  int b, off0; sw_decode(blockIdx.x, NBLK, b, off0);
  const int lane = tid & 63, wave = tid >> 6;
  const int l15 = lane & 15, lg = lane >> 4;
  const size_t bb = (size_t)b*V;
  const unsigned short* aBase = &sW[l15*KP + lg*8];

  for (int off = off0; off < NT; off += NBLK){
    const int vbase = off*256 + wave*64;
    int vr[4], vc[4];
    const unsigned short* bp[4];
    #pragma unroll
    for (int j=0;j<4;++j){
      vr[j] = vbase + j*16 + l15;
      vc[j] = min(vr[j], V-1);
      bp[j] = in + (bb + vc[j])*K + lg*8;
    }

    f32x4 acc[NF][4];
    #pragma unroll
    for (int nf=0; nf<NF; ++nf)
      #pragma unroll
      for (int j=0;j<4;++j) acc[nf][j] = (f32x4)0.f;

    #pragma unroll
    for (int ks=0; ks<KS; ++ks){
      short8v bv[4];
      #pragma unroll
      for (int j=0;j<4;++j) bv[j] = *reinterpret_cast<const short8v*>(bp[j] + ks*32);
      #pragma unroll
      for (int nf=0; nf<NF; ++nf){
        short8v a = *reinterpret_cast<const short8v*>(aBase + nf*16*KP + ks*32);
        #pragma unroll
        for (int j=0;j<4;++j)
          acc[nf][j] = __builtin_amdgcn_mfma_f32_16x16x32_bf16(a, bv[j], acc[nf][j], 0,0,0);
      }
    }

    #pragma unroll
    for (int j=0;j<4;++j){
      if (vr[j] >= V) continue;
      float ds = dvec[vc[j]];
      #pragma unroll
      for (int nf=0; nf<NF; ++nf){
        int nb = nf*16 + lg*4;
        ushort4v o;
        #pragma unroll
        for (int reg=0; reg<4; ++reg){
          float val = acc[nf][j][reg] + ds*sB[nb + reg];
          if (RELU) val = val > 0.f ? val : 0.f;
          o[reg] = f2bf(val);
        }
        *reinterpret_cast<ushort4v*>(out + (bb + vr[j])*N + nb) = o;
      }
    }
  }
}

// ---- layer-3 linear + relu + mean-pool, persistent weights + tile loop ----
__global__ __launch_bounds__(256) void lin3_mean_k(const unsigned short* __restrict__ in,
    const float* __restrict__ W, const float* __restrict__ bias,
    const float* __restrict__ dvec, float* __restrict__ g, int V, int NBLK, int NT){
  constexpr int K = 64, N = 128, KP = K + 8, NF = N/16, KS = K/32;
  __shared__ unsigned short sW[N * KP];
  __shared__ float sB[N];
  __shared__ float gPart[128];
  int tid = threadIdx.x;
  for (int i = tid*4; i < N*K; i += 1024){
    const float4 wv = *reinterpret_cast<const float4*>(W + i);
    int n = i / K, k = i - n*K;
    unsigned short* dst = &sW[n*KP + k];
    dst[0] = f2bf(wv.x); dst[1] = f2bf(wv.y); dst[2] = f2bf(wv.z); dst[3] = f2bf(wv.w);
  }
  if (tid < N) sB[tid] = bias[tid];
  if (tid < 128) gPart[tid] = 0.f;
  __syncthreads();

  int b, off0; sw_decode(blockIdx.x, NBLK, b, off0);
  const int lane = tid & 63, wave = tid >> 6;
  const int l15 = lane & 15, lg = lane >> 4;
  const size_t bb = (size_t)b*V;
  const unsigned short* aBase = &sW[l15*KP + lg*8];

  float racc[NF][4];
  #pragma unroll
  for (int nf=0;nf<NF;++nf)
    #pragma unroll
    for (int reg=0;reg<4;++reg) racc[nf][reg] = 0.f;

  for (int off = off0; off < NT; off += NBLK){
    const int vbase = off*128 + wave*32;
    int v0r = vbase + l15, v1r = vbase + 16 + l15;
    int v0c = min(v0r, V-1), v1c = min(v1r, V-1);
    const unsigned short* bp0 = in + (bb + v0c)*K + lg*8;
    const unsigned short* bp1 = in + (bb + v1c)*K + lg*8;

    f32x4 acc[NF][2];
    #pragma unroll
    for (int nf=0; nf<NF; ++nf){ acc[nf][0] = (f32x4)0.f; acc[nf][1] = (f32x4)0.f; }

    #pragma unroll
    for (int ks=0; ks<KS; ++ks){
      short8v b0 = *reinterpret_cast<const short8v*>(bp0 + ks*32);
      short8v b1 = *reinterpret_cast<const short8v*>(bp1 + ks*32);
      #pragma unroll
      for (int nf=0; nf<NF; ++nf){
        short8v a = *reinterpret_cast<const short8v*>(aBase + nf*16*KP + ks*32);
        acc[nf][0] = __builtin_amdgcn_mfma_f32_16x16x32_bf16(a, b0, acc[nf][0], 0,0,0);
        acc[nf][1] = __builtin_amdgcn_mfma_f32_16x16x32_bf16(a, b1, acc[nf][1], 0,0,0);
      }
    }

    bool ok0 = v0r < V, ok1 = v1r < V;
    float d0 = dvec[v0c], d1 = dvec[v1c];
    #pragma unroll
    for (int nf=0; nf<NF; ++nf){
      #pragma unroll
      for (int reg=0; reg<4; ++reg){
        int c = nf*16 + lg*4 + reg;
        float v0f = fmaxf(acc[nf][0][reg] + d0*sB[c], 0.f);
        float v1f = fmaxf(acc[nf][1][reg] + d1*sB[c], 0.f);
        racc[nf][reg] += (ok0 ? v0f : 0.f) + (ok1 ? v1f : 0.f);
      }
    }
  }

  #pragma unroll
  for (int nf=0; nf<NF; ++nf){
    #pragma unroll
    for (int reg=0; reg<4; ++reg){
      int c = nf*16 + lg*4 + reg;
      float sA = racc[nf][reg];
      #pragma unroll
      for (int m=1; m<16; m<<=1) sA += __shfl_xor(sA, m);
      if (l15 == 0) atomicAdd(&gPart[c], sA);
    }
  }
  __syncthreads();
  if (tid < 128){
    float a = gPart[tid];
    if (a != 0.f) atomicAdd(&g[b*128 + tid], a);
  }
}

// ---- fused VAE head: one block per batch element; emits mu, lv, zp ----
__global__ __launch_bounds__(256) void head2_k(const float* __restrict__ g,
    const float* __restrict__ Wfc, const float* __restrict__ bfc,
    const float* __restrict__ Wmu, const float* __restrict__ bmu,
    const float* __restrict__ Wlv, const float* __restrict__ blv,
    const float* __restrict__ eps, const float* __restrict__ Wd1,
    const float* __restrict__ bd1, float* __restrict__ mu_out,
    float* __restrict__ lv_out, float* __restrict__ zp, float invV){
  int b = blockIdx.x;
  int tid = threadIdx.x;
  __shared__ float sG[128];
  __shared__ float sF[256];
  __shared__ float sMu[32];
  __shared__ float sLv[32];
  __shared__ float sZ[32];
  if (tid < 128) sG[tid] = g[b*128 + tid] * invV;
  __syncthreads();
  {
    const float4* wr = reinterpret_cast<const float4*>(Wfc + tid*128);
    float acc = bfc[tid];
    #pragma unroll 8
    for (int k4=0;k4<32;k4++){
      float4 wv = wr[k4];
      acc += sG[k4*4]*wv.x + sG[k4*4+1]*wv.y + sG[k4*4+2]*wv.z + sG[k4*4+3]*wv.w;
    }
    sF[tid] = fmaxf(acc, 0.f);
  }
  __syncthreads();
  if (tid < 64){
    int c = tid & 31;
    bool isMu = tid < 32;
    const float4* wr = reinterpret_cast<const float4*>((isMu ? Wmu : Wlv) + c*256);
    float acc = isMu ? bmu[c] : blv[c];
    #pragma unroll 8
    for (int k4=0;k4<64;k4++){
      float4 wv = wr[k4];
      acc += sF[k4*4]*wv.x + sF[k4*4+1]*wv.y + sF[k4*4+2]*wv.z + sF[k4*4+3]*wv.w;
    }
    if (isMu){ sMu[c] = acc; mu_out[b*32+c] = acc; }
    else {
      acc = fminf(20.f, fmaxf(-20.f, acc));
      sLv[c] = acc; lv_out[b*32+c] = acc;
    }
  }
  __syncthreads();
  if (tid < 32) sZ[tid] = sMu[tid] + eps[b*32+tid]*expf(0.5f*sLv[tid]);
  __syncthreads();
  if (tid < 128){
    const float* wr = Wd1 + tid*35;
    float acc = bd1[tid];
    #pragma unroll
    for (int k=0;k<32;k++) acc += sZ[k]*wr[k];
    zp[b*128 + tid] = acc;
  }
}

// ---- FULL decoder: persistent Wd2+Wd3 in LDS, barrier-free tile loop (sH wave-private) ----
__global__ __launch_bounds__(256) void dec_k(const float* __restrict__ zp,
    const float* __restrict__ tmpl, const float* __restrict__ Wd1,
    const float* __restrict__ Wd2, const float* __restrict__ bd2,
    const float* __restrict__ Wd3, const float* __restrict__ bd3,
    const float* __restrict__ Wd4, const float* __restrict__ bd4,
    float* __restrict__ out, int V, int NBLK, int NT){
  constexpr int KP = 136;
  __shared__ unsigned short sW2[128*KP];  // 34.8 KB, full Wd2
  __shared__ unsigned short sW3[64*KP];   // 17.4 KB
  __shared__ unsigned short sH[64*KP];    // 17.4 KB, wave-private 16-row slices
  __shared__ float sB2[128];
  __shared__ float sB3[64];
  __shared__ float sW4[192];
  __shared__ float sB4v[4];
  __shared__ float sZPb[128];
  __shared__ float sWT[128*3];
  int tid = threadIdx.x;
  int b, off0; sw_decode(blockIdx.x, NBLK, b, off0);

  if (tid < 128) sB2[tid] = bd2[tid];
  if (tid < 64)  sB3[tid] = bd3[tid];
  if (tid < 192) sW4[tid] = Wd4[tid];
  if (tid < 3)   sB4v[tid] = bd4[tid];
  if (tid < 128) sZPb[tid] = zp[b*128 + tid];
  if (tid < 128){
    sWT[tid*3+0] = Wd1[tid*35+32];
    sWT[tid*3+1] = Wd1[tid*35+33];
    sWT[tid*3+2] = Wd1[tid*35+34];
  }
  for (int i = tid*4; i < 128*128; i += 1024){
    float4 wv = *reinterpret_cast<const float4*>(Wd2 + i);
    int n = i >> 7, k = i & 127;
    unsigned short* dst = &sW2[n*KP + k];
    dst[0]=f2bf(wv.x); dst[1]=f2bf(wv.y); dst[2]=f2bf(wv.z); dst[3]=f2bf(wv.w);
  }
  for (int i = tid*4; i < 64*128; i += 1024){
    float4 wv = *reinterpret_cast<const float4*>(Wd3 + i);
    int n = i >> 7, k = i & 127;
    unsigned short* dst = &sW3[n*KP + k];
    dst[0]=f2bf(wv.x); dst[1]=f2bf(wv.y); dst[2]=f2bf(wv.z); dst[3]=f2bf(wv.w);
  }
  __syncthreads();

  const int wave = tid >> 6, lane = tid & 63;
  const int l15 = lane & 15, lg = lane >> 4;
  const int lrow = wave*16;
  const unsigned short* a2Base = &sW2[l15*KP + lg*8];
  const unsigned short* a3Base = &sW3[l15*KP + lg*8];

  for (int off = off0; off < NT; off += NBLK){
    const int vbase = off*64 + wave*16;
    int v0r = vbase + l15;
    int v0 = min(v0r, V-1);
    float t0x=tmpl[v0*3], t0y=tmpl[v0*3+1], t0z=tmpl[v0*3+2];

    // hd1 B-fragment
    short8v bf0[4];
    #pragma unroll
    for (int ks=0; ks<4; ++ks){
      #pragma unroll
      for (int k=0;k<8;k++){
        int c = lg*8 + ks*32 + k;
        const float* wt = &sWT[c*3];
        bf0[ks][k] = (short)f2bf(fmaxf(sZPb[c] + t0x*wt[0]+t0y*wt[1]+t0z*wt[2], 0.f));
      }
    }

    // dec2: full 128 output channels in one pass
    f32x4 acc[8];
    #pragma unroll
    for (int nf=0; nf<8; ++nf) acc[nf]=(f32x4)0.f;
    #pragma unroll
    for (int ks=0; ks<4; ++ks){
      #pragma unroll
      for (int nf=0; nf<8; ++nf){
        short8v a = *reinterpret_cast<const short8v*>(a2Base + nf*16*KP + ks*32);
        acc[nf] = __builtin_amdgcn_mfma_f32_16x16x32_bf16(a, bf0[ks], acc[nf], 0,0,0);
      }
    }
    #pragma unroll
    for (int nf=0; nf<8; ++nf){
      int c = nf*16 + lg*4;
      ushort4v o;
      #pragma unroll
      for (int reg=0; reg<4; ++reg)
        o[reg] = f2bf(fmaxf(acc[nf][reg] + sB2[c+reg], 0.f));
      *reinterpret_cast<ushort4v*>(&sH[(lrow + l15)*KP + c]) = o;
    }
    // no barrier: sH rows [lrow, lrow+16) are written and read only by this wave

    // dec3 (K=128 from wave-private sH)
    f32x4 acc3[4];
    #pragma unroll
    for (int nf=0; nf<4; ++nf) acc3[nf]=(f32x4)0.f;
    #pragma unroll
    for (int ks=0; ks<4; ++ks){
      short8v h0 = *reinterpret_cast<const short8v*>(&sH[(lrow + l15)*KP + ks*32 + lg*8]);
      #pragma unroll
      for (int nf=0; nf<4; ++nf){
        short8v a = *reinterpret_cast<const short8v*>(a3Base + nf*16*KP + ks*32);
        acc3[nf] = __builtin_amdgcn_mfma_f32_16x16x32_bf16(a, h0, acc3[nf], 0,0,0);
      }
    }

    // fused dec4 epilogue
    float p0 = 0.f, p1 = 0.f, p2 = 0.f;
    #pragma unroll
    for (int nf=0; nf<4; ++nf){
      #pragma unroll
      for (int reg=0; reg<4; ++reg){
        int c = nf*16 + lg*4 + reg;
        float h = fmaxf(acc3[nf][reg] + sB3[c], 0.f);
        p0 += h*sW4[c]; p1 += h*sW4[64+c]; p2 += h*sW4[128+c];
      }
    }
    p0 += __shfl_xor(p0,16); p0 += __shfl_xor(p0,32);
    p1 += __shfl_xor(p1,16); p1 += __shfl_xor(p1,32);
    p2 += __shfl_xor(p2,16); p2 += __shfl_xor(p2,32);
    if (lg == 0 && v0r < V){
      size_t o = ((size_t)b*V + v0r)*3;
      out[o+0] = tmpl[v0r*3+0] + p0 + sB4v[0];
      out[o+1] = tmpl[v0r*3+1] + p1 + sB4v[1];
      out[o+2] = tmpl[v0r*3+2] + p2 + sB4v[2];
    }
  }
}

extern "C" void kernel_launch(void* const* d_in, const int* in_sizes, int n_in,
                              void* d_out, int out_size, void* d_ws, size_t ws_size,
                              hipStream_t stream){
  const float* x    = (const float*)d_in[0];
  const float* eps  = (const float*)d_in[1];
  const int*   row  = (const int*)d_in[2];
  const int*   colx = (const int*)d_in[3];
  const float* vals = (const float*)d_in[4];
  const float* tmpl = (const float*)d_in[5];
  const float* W1 = (const float*)d_in[6];  const float* b1 = (const float*)d_in[7];
  const float* W2 = (const float*)d_in[8];  const float* b2 = (const float*)d_in[9];
  const float* W3 = (const float*)d_in[10]; const float* b3 = (const float*)d_in[11];
  const float* Wfc= (const float*)d_in[12]; const float* bfc= (const float*)d_in[13];
  const float* Wmu= (const float*)d_in[14]; const float* bmu= (const float*)d_in[15];
  const float* Wlv= (const float*)d_in[16]; const float* blv= (const float*)d_in[17];
  const float* Wd1= (const float*)d_in[18]; const float* bd1= (const float*)d_in[19];
  const float* Wd2= (const float*)d_in[20]; const float* bd2= (const float*)d_in[21];
  const float* Wd3= (const float*)d_in[22]; const float* bd3= (const float*)d_in[23];
  const float* Wd4= (const float*)d_in[24]; const float* bd4= (const float*)d_in[25];

  int V   = in_sizes[5] / 3;     // 10242
  int Bn  = in_sizes[1] / 32;    // 16
  int nnz = in_sizes[2];         // 71682
  int R   = Bn * V;              // 163872 (b-major rows: r = b*V + v)

  // workspace layout
  char* w = (char*)d_ws;
  size_t off = 0;
  auto alloc = [&](size_t bytes)->char*{
    char* p = w + off; off = (off + bytes + 255) & ~(size_t)255; return p;
  };
  unsigned short* bufA = (unsigned short*)alloc((size_t)R * 64 * 2);
  unsigned short* bufB = (unsigned short*)alloc((size_t)R * 64 * 2);
  int*   col8 = (int*)alloc((size_t)V*8*4);
  float* val8 = (float*)alloc((size_t)V*8*4);
  float* dvec = (float*)alloc((size_t)V*4);
  float* g    = (float*)alloc((size_t)Bn*128*4);
  float* zpb  = (float*)alloc((size_t)Bn*128*4);

  float* recon  = (float*)d_out;
  float* mu_out = recon + (size_t)R*3;
  float* lv_out = mu_out + (size_t)Bn*32;

  int NB1  = (V + 255) / 256;       // spmm_lin1: 256 rows/block
  int NB16 = (V*4 + 255) / 256;     // spmm16s: 64 rows/block
  int NTm  = (V + 255) / 256;       // lin MFMA tiles (256 vertices)
  int NTm3 = (V + 127) / 128;       // lin3 tiles (128 vertices)
  int NTd  = (V + 63) / 64;         // dec tiles (64 vertices)
  int NBLK = 32;                    // blocks per batch for persistent-weight kernels

  // prep (col8/val8/dvec + zero g)
  prep_k<<<(V+255)/256, 256, 0, stream>>>(row, colx, vals, nnz, col8, val8, dvec, g, V, Bn*128);

  // encoder (all XCD-affine: batch b on XCD b%8)
  spmm_lin1_k<<<16*NB1, 256, 0, stream>>>(x, col8, val8, dvec, W1, b1, bufA, V, NB1);
  spmm16s_k<<<16*NB16, 256, 0, stream>>>(bufA, bufB, col8, val8, V, NB16);
  lin_mfma_k<64,64,true><<<16*NBLK, 256, 0, stream>>>(bufB, W2, b2, bufA, dvec, V, NBLK, NTm);
  spmm16s_k<<<16*NB16, 256, 0, stream>>>(bufA, bufB, col8, val8, V, NB16);
  lin3_mean_k<<<16*NBLK, 256, 0, stream>>>(bufB, W3, b3, dvec, g, V, NBLK, NTm3);

  // head (feat/mu/lv/z/zpart)
  head2_k<<<Bn, 256, 0, stream>>>(g, Wfc, bfc, Wmu, bmu, Wlv, blv, eps, Wd1, bd1,
                                  mu_out, lv_out, zpb, 1.0f/(float)V);

  // full decoder: persistent weights, barrier-free tile loop
  dec_k<<<16*NBLK, 256, 0, stream>>>(zpb, tmpl, Wd1, Wd2, bd2, Wd3, bd3, Wd4, bd4,
                                     recon, V, NBLK, NTd);
}

// Round 13
// 126.203 us; speedup vs baseline: 1.0251x; 1.0251x over previous
//
#include <hip/hip_runtime.h>
#include <hip/hip_bf16.h>

typedef __attribute__((ext_vector_type(8))) unsigned short ushort8;
typedef __attribute__((ext_vector_type(4))) unsigned short ushort4v;
typedef __attribute__((ext_vector_type(8))) short short8v;
typedef __attribute__((ext_vector_type(4))) float f32x4;

__device__ __forceinline__ float bf2f(unsigned short u){
  union { unsigned int i; float f; } x; x.i = ((unsigned int)u) << 16; return x.f;
}
__device__ __forceinline__ unsigned short f2bf(float f){
  __hip_bfloat16 h = __float2bfloat16(f);
  return *reinterpret_cast<unsigned short*>(&h);
}

// XCD-affine block decode: p%8 = XCD slot; each XCD owns batches {xcd, xcd+8}.
__device__ __forceinline__ void sw_decode(int p, int NB, int& b, int& off){
  int xcd = p & 7, q = p >> 3;
  int hi = (q >= NB) ? 1 : 0;
  b = xcd + (hi << 3);
  off = q - (hi ? NB : 0);
}

// ---- prep: col8/val8 (deg padded to 8) via binary searches; dvec; zero g ----
__global__ void prep_k(const int* __restrict__ row, const int* __restrict__ colx,
                       const float* __restrict__ vals, int nnz,
                       int* __restrict__ col8, float* __restrict__ val8,
                       float* __restrict__ dvec, float* __restrict__ g, int V, int GN){
  int v = blockIdx.x*256 + threadIdx.x;
  if (v < GN) g[v] = 0.f;
  if (v >= V) return;
  int lo = 0, hi = nnz;
  while (lo < hi){ int m = (lo+hi)>>1; if (row[m] < v) lo = m+1; else hi = m; }
  int e0 = lo;
  int lo2 = e0; hi = nnz;
  while (lo2 < hi){ int m = (lo2+hi)>>1; if (row[m] < v+1) lo2 = m+1; else hi = m; }
  int e1 = lo2;
  float s = 0.f;
  #pragma unroll
  for (int i=0;i<8;i++){
    int e = e0 + i;
    int c  = (e < e1) ? colx[e] : 0;
    float wv = (e < e1) ? vals[e] : 0.f;
    col8[v*8+i] = c; val8[v*8+i] = wv; s += wv;
  }
  dvec[v] = s;
}

__device__ __forceinline__ void load_nbr(const int* __restrict__ col8,
    const float* __restrict__ val8, int v, int* cols, float* vv){
  int4 ca = *reinterpret_cast<const int4*>(col8 + v*8);
  int4 cb = *reinterpret_cast<const int4*>(col8 + v*8 + 4);
  float4 va = *reinterpret_cast<const float4*>(val8 + v*8);
  float4 vb = *reinterpret_cast<const float4*>(val8 + v*8 + 4);
  cols[0]=ca.x; cols[1]=ca.y; cols[2]=ca.z; cols[3]=ca.w;
  cols[4]=cb.x; cols[5]=cb.y; cols[6]=cb.z;
  vv[0]=va.x; vv[1]=va.y; vv[2]=va.z; vv[3]=va.w;
  vv[4]=vb.x; vv[5]=vb.y; vv[6]=vb.z;
}

// ---- layer1 (XCD-affine): h1[b*V+v] = relu(spmm(x)@W1^T + d*b1) ----
__global__ void spmm_lin1_k(const float* __restrict__ x, const int* __restrict__ col8,
    const float* __restrict__ val8, const float* __restrict__ d,
    const float* __restrict__ W1, const float* __restrict__ b1,
    unsigned short* __restrict__ out, int V, int NB){
  __shared__ float sW[192];
  __shared__ float sB[64];
  int tid = threadIdx.x;
  if (tid < 192) sW[tid] = W1[tid];
  if (tid < 64)  sB[tid] = b1[tid];
  __syncthreads();
  int b, off; sw_decode(blockIdx.x, NB, b, off);
  int v = off*256 + tid;
  if (v >= V) return;
  const float* xb = x + (size_t)b*V*3;
  int   cs[7]; float ws[7];
  load_nbr(col8, val8, v, cs, ws);
  float s0=0.f, s1=0.f, s2=0.f;
  #pragma unroll
  for (int i=0;i<7;i++){
    const float* xr = xb + (size_t)cs[i]*3;
    s0 += ws[i]*xr[0]; s1 += ws[i]*xr[1]; s2 += ws[i]*xr[2];
  }
  float dv = d[v];
  unsigned short* orow = out + ((size_t)b*V + v)*64;
  #pragma unroll
  for (int cg=0; cg<8; ++cg){
    ushort8 o;
    #pragma unroll
    for (int k=0;k<8;k++){
      int c = cg*8 + k;
      float acc = dv*sB[c] + s0*sW[c*3] + s1*sW[c*3+1] + s2*sW[c*3+2];
      o[k] = f2bf(fmaxf(acc, 0.f));
    }
    *reinterpret_cast<ushort8*>(orow + cg*8) = o;
  }
}

// ---- SPMM deg-7, 8ch/thread, XCD-affine, vector index loads ----
__global__ __launch_bounds__(256) void spmm8s_k(const unsigned short* __restrict__ in,
    unsigned short* __restrict__ out, const int* __restrict__ col8,
    const float* __restrict__ val8, int V, int NB){
  int b, off; sw_decode(blockIdx.x, NB, b, off);
  int j = off*256 + (int)threadIdx.x;
  if (j >= V*8) return;
  int cg = j & 7; int v = j >> 3;
  const unsigned short* base = in + (size_t)b*V*64 + cg*8;
  int cols[7]; float vv[7];
  load_nbr(col8, val8, v, cols, vv);
  ushort8 g[7];
  #pragma unroll
  for (int i=0;i<7;i++) g[i] = *reinterpret_cast<const ushort8*>(base + (size_t)cols[i]*64);
  float acc[8];
  #pragma unroll
  for (int k=0;k<8;k++) acc[k] = 0.f;
  #pragma unroll
  for (int i=0;i<7;i++){
    float s = vv[i];
    #pragma unroll
    for (int k=0;k<8;k++) acc[k] += s*bf2f(g[i][k]);
  }
  ushort8 o;
  #pragma unroll
  for (int k=0;k<8;k++) o[k] = f2bf(acc[k]);
  *reinterpret_cast<ushort8*>(out + ((size_t)b*V + v)*64 + cg*8) = o;
}

// ---- MFMA dense linear, persistent weights + tile loop, XCD-affine ----
template<int K, int N, bool RELU>
__global__ __launch_bounds__(256) void lin_mfma_k(const unsigned short* __restrict__ in,
    const float* __restrict__ W, const float* __restrict__ bias,
    unsigned short* __restrict__ out, const float* __restrict__ dvec, int V,
    int NBLK, int NT){
  constexpr int KP = K + 8;
  constexpr int NF = N / 16;
  constexpr int KS = K / 32;
  __shared__ unsigned short sW[N * KP];
  __shared__ float sB[N];
  int tid = threadIdx.x;
  for (int i = tid*4; i < N*K; i += 1024){
    const float4 wv = *reinterpret_cast<const float4*>(W + i);
    int n = i / K, k = i - n*K;
    unsigned short* dst = &sW[n*KP + k];
    dst[0] = f2bf(wv.x); dst[1] = f2bf(wv.y); dst[2] = f2bf(wv.z); dst[3] = f2bf(wv.w);
  }
  if (tid < N) sB[tid] = bias[tid];
  __syncthreads();

  int b, off0; sw_decode(blockIdx.x, NBLK, b, off0);
  const int lane = tid & 63, wave = tid >> 6;
  const int l15 = lane & 15, lg = lane >> 4;
  const size_t bb = (size_t)b*V;
  const unsigned short* aBase = &sW[l15*KP + lg*8];

  for (int off = off0; off < NT; off += NBLK){
    const int vbase = off*128 + wave*32;
    int v0r = vbase + l15, v1r = vbase + 16 + l15;
    int v0c = min(v0r, V-1), v1c = min(v1r, V-1);
    const unsigned short* bp0 = in + (bb + v0c)*K + lg*8;
    const unsigned short* bp1 = in + (bb + v1c)*K + lg*8;

    f32x4 acc[NF][2];
    #pragma unroll
    for (int nf=0; nf<NF; ++nf){ acc[nf][0] = (f32x4)0.f; acc[nf][1] = (f32x4)0.f; }

    #pragma unroll
    for (int ks=0; ks<KS; ++ks){
      short8v b0 = *reinterpret_cast<const short8v*>(bp0 + ks*32);
      short8v b1 = *reinterpret_cast<const short8v*>(bp1 + ks*32);
      #pragma unroll
      for (int nf=0; nf<NF; ++nf){
        short8v a = *reinterpret_cast<const short8v*>(aBase + nf*16*KP + ks*32);
        acc[nf][0] = __builtin_amdgcn_mfma_f32_16x16x32_bf16(a, b0, acc[nf][0], 0,0,0);
        acc[nf][1] = __builtin_amdgcn_mfma_f32_16x16x32_bf16(a, b1, acc[nf][1], 0,0,0);
      }
    }

    float d0 = dvec[v0c], d1 = dvec[v1c];
    #pragma unroll
    for (int rr=0; rr<2; ++rr){
      int v = rr ? v1r : v0r;
      if (v >= V) continue;
      float ds = rr ? d1 : d0;
      #pragma unroll
      for (int nf=0; nf<NF; ++nf){
        int nb = nf*16 + lg*4;
        ushort4v o;
        #pragma unroll
        for (int reg=0; reg<4; ++reg){
          float val = acc[nf][rr][reg] + ds*sB[nb + reg];
          if (RELU) val = val > 0.f ? val : 0.f;
          o[reg] = f2bf(val);
        }
        *reinterpret_cast<ushort4v*>(out + (bb + v)*N + nb) = o;
      }
    }
  }
}

// ---- layer-3 linear + relu + mean-pool, persistent weights + tile loop ----
__global__ __launch_bounds__(256) void lin3_mean_k(const unsigned short* __restrict__ in,
    const float* __restrict__ W, const float* __restrict__ bias,
    const float* __restrict__ dvec, float* __restrict__ g, int V, int NBLK, int NT){
  constexpr int K = 64, N = 128, KP = K + 8, NF = N/16, KS = K/32;
  __shared__ unsigned short sW[N * KP];
  __shared__ float sB[N];
  __shared__ float gPart[128];
  int tid = threadIdx.x;
  for (int i = tid*4; i < N*K; i += 1024){
    const float4 wv = *reinterpret_cast<const float4*>(W + i);
    int n = i / K, k = i - n*K;
    unsigned short* dst = &sW[n*KP + k];
    dst[0] = f2bf(wv.x); dst[1] = f2bf(wv.y); dst[2] = f2bf(wv.z); dst[3] = f2bf(wv.w);
  }
  if (tid < N) sB[tid] = bias[tid];
  if (tid < 128) gPart[tid] = 0.f;
  __syncthreads();

  int b, off0; sw_decode(blockIdx.x, NBLK, b, off0);
  const int lane = tid & 63, wave = tid >> 6;
  const int l15 = lane & 15, lg = lane >> 4;
  const size_t bb = (size_t)b*V;
  const unsigned short* aBase = &sW[l15*KP + lg*8];

  float racc[NF][4];
  #pragma unroll
  for (int nf=0;nf<NF;++nf)
    #pragma unroll
    for (int reg=0;reg<4;++reg) racc[nf][reg] = 0.f;

  for (int off = off0; off < NT; off += NBLK){
    const int vbase = off*128 + wave*32;
    int v0r = vbase + l15, v1r = vbase + 16 + l15;
    int v0c = min(v0r, V-1), v1c = min(v1r, V-1);
    const unsigned short* bp0 = in + (bb + v0c)*K + lg*8;
    const unsigned short* bp1 = in + (bb + v1c)*K + lg*8;

    f32x4 acc[NF][2];
    #pragma unroll
    for (int nf=0; nf<NF; ++nf){ acc[nf][0] = (f32x4)0.f; acc[nf][1] = (f32x4)0.f; }

    #pragma unroll
    for (int ks=0; ks<KS; ++ks){
      short8v b0 = *reinterpret_cast<const short8v*>(bp0 + ks*32);
      short8v b1 = *reinterpret_cast<const short8v*>(bp1 + ks*32);
      #pragma unroll
      for (int nf=0; nf<NF; ++nf){
        short8v a = *reinterpret_cast<const short8v*>(aBase + nf*16*KP + ks*32);
        acc[nf][0] = __builtin_amdgcn_mfma_f32_16x16x32_bf16(a, b0, acc[nf][0], 0,0,0);
        acc[nf][1] = __builtin_amdgcn_mfma_f32_16x16x32_bf16(a, b1, acc[nf][1], 0,0,0);
      }
    }

    bool ok0 = v0r < V, ok1 = v1r < V;
    float d0 = dvec[v0c], d1 = dvec[v1c];
    #pragma unroll
    for (int nf=0; nf<NF; ++nf){
      #pragma unroll
      for (int reg=0; reg<4; ++reg){
        int c = nf*16 + lg*4 + reg;
        float v0f = fmaxf(acc[nf][0][reg] + d0*sB[c], 0.f);
        float v1f = fmaxf(acc[nf][1][reg] + d1*sB[c], 0.f);
        racc[nf][reg] += (ok0 ? v0f : 0.f) + (ok1 ? v1f : 0.f);
      }
    }
  }

  #pragma unroll
  for (int nf=0; nf<NF; ++nf){
    #pragma unroll
    for (int reg=0; reg<4; ++reg){
      int c = nf*16 + lg*4 + reg;
      float sA = racc[nf][reg];
      #pragma unroll
      for (int m=1; m<16; m<<=1) sA += __shfl_xor(sA, m);
      if (l15 == 0) atomicAdd(&gPart[c], sA);
    }
  }
  __syncthreads();
  if (tid < 128){
    float a = gPart[tid];
    if (a != 0.f) atomicAdd(&g[b*128 + tid], a);
  }
}

// ---- fused VAE head: one block per batch element; emits mu, lv, zp ----
__global__ __launch_bounds__(256) void head2_k(const float* __restrict__ g,
    const float* __restrict__ Wfc, const float* __restrict__ bfc,
    const float* __restrict__ Wmu, const float* __restrict__ bmu,
    const float* __restrict__ Wlv, const float* __restrict__ blv,
    const float* __restrict__ eps, const float* __restrict__ Wd1,
    const float* __restrict__ bd1, float* __restrict__ mu_out,
    float* __restrict__ lv_out, float* __restrict__ zp, float invV){
  int b = blockIdx.x;
  int tid = threadIdx.x;
  __shared__ float sG[128];
  __shared__ float sF[256];
  __shared__ float sMu[32];
  __shared__ float sLv[32];
  __shared__ float sZ[32];
  if (tid < 128) sG[tid] = g[b*128 + tid] * invV;
  __syncthreads();
  {
    const float4* wr = reinterpret_cast<const float4*>(Wfc + tid*128);
    float acc = bfc[tid];
    #pragma unroll 8
    for (int k4=0;k4<32;k4++){
      float4 wv = wr[k4];
      acc += sG[k4*4]*wv.x + sG[k4*4+1]*wv.y + sG[k4*4+2]*wv.z + sG[k4*4+3]*wv.w;
    }
    sF[tid] = fmaxf(acc, 0.f);
  }
  __syncthreads();
  if (tid < 64){
    int c = tid & 31;
    bool isMu = tid < 32;
    const float4* wr = reinterpret_cast<const float4*>((isMu ? Wmu : Wlv) + c*256);
    float acc = isMu ? bmu[c] : blv[c];
    #pragma unroll 8
    for (int k4=0;k4<64;k4++){
      float4 wv = wr[k4];
      acc += sF[k4*4]*wv.x + sF[k4*4+1]*wv.y + sF[k4*4+2]*wv.z + sF[k4*4+3]*wv.w;
    }
    if (isMu){ sMu[c] = acc; mu_out[b*32+c] = acc; }
    else {
      acc = fminf(20.f, fmaxf(-20.f, acc));
      sLv[c] = acc; lv_out[b*32+c] = acc;
    }
  }
  __syncthreads();
  if (tid < 32) sZ[tid] = sMu[tid] + eps[b*32+tid]*expf(0.5f*sLv[tid]);
  __syncthreads();
  if (tid < 128){
    const float* wr = Wd1 + tid*35;
    float acc = bd1[tid];
    #pragma unroll
    for (int k=0;k<32;k++) acc += sZ[k]*wr[k];
    zp[b*128 + tid] = acc;
  }
}

// ---- FULL decoder: persistent Wd2+Wd3 in LDS, barrier-free tile loop (sH wave-private) ----
__global__ __launch_bounds__(256) void dec_k(const float* __restrict__ zp,
    const float* __restrict__ tmpl, const float* __restrict__ Wd1,
    const float* __restrict__ Wd2, const float* __restrict__ bd2,
    const float* __restrict__ Wd3, const float* __restrict__ bd3,
    const float* __restrict__ Wd4, const float* __restrict__ bd4,
    float* __restrict__ out, int V, int NBLK, int NT){
  constexpr int KP = 136;
  __shared__ unsigned short sW2[128*KP];  // 34.8 KB, full Wd2
  __shared__ unsigned short sW3[64*KP];   // 17.4 KB
  __shared__ unsigned short sH[64*KP];    // 17.4 KB, wave-private 16-row slices
  __shared__ float sB2[128];
  __shared__ float sB3[64];
  __shared__ float sW4[192];
  __shared__ float sB4v[4];
  __shared__ float sZPb[128];
  __shared__ float sWT[128*3];
  int tid = threadIdx.x;
  int b, off0; sw_decode(blockIdx.x, NBLK, b, off0);

  if (tid < 128) sB2[tid] = bd2[tid];
  if (tid < 64)  sB3[tid] = bd3[tid];
  if (tid < 192) sW4[tid] = Wd4[tid];
  if (tid < 3)   sB4v[tid] = bd4[tid];
  if (tid < 128) sZPb[tid] = zp[b*128 + tid];
  if (tid < 128){
    sWT[tid*3+0] = Wd1[tid*35+32];
    sWT[tid*3+1] = Wd1[tid*35+33];
    sWT[tid*3+2] = Wd1[tid*35+34];
  }
  for (int i = tid*4; i < 128*128; i += 1024){
    float4 wv = *reinterpret_cast<const float4*>(Wd2 + i);
    int n = i >> 7, k = i & 127;
    unsigned short* dst = &sW2[n*KP + k];
    dst[0]=f2bf(wv.x); dst[1]=f2bf(wv.y); dst[2]=f2bf(wv.z); dst[3]=f2bf(wv.w);
  }
  for (int i = tid*4; i < 64*128; i += 1024){
    float4 wv = *reinterpret_cast<const float4*>(Wd3 + i);
    int n = i >> 7, k = i & 127;
    unsigned short* dst = &sW3[n*KP + k];
    dst[0]=f2bf(wv.x); dst[1]=f2bf(wv.y); dst[2]=f2bf(wv.z); dst[3]=f2bf(wv.w);
  }
  __syncthreads();

  const int wave = tid >> 6, lane = tid & 63;
  const int l15 = lane & 15, lg = lane >> 4;
  const int lrow = wave*16;
  const unsigned short* a2Base = &sW2[l15*KP + lg*8];
  const unsigned short* a3Base = &sW3[l15*KP + lg*8];

  for (int off = off0; off < NT; off += NBLK){
    const int vbase = off*64 + wave*16;
    int v0r = vbase + l15;
    int v0 = min(v0r, V-1);
    float t0x=tmpl[v0*3], t0y=tmpl[v0*3+1], t0z=tmpl[v0*3+2];

    // hd1 B-fragment
    short8v bf0[4];
    #pragma unroll
    for (int ks=0; ks<4; ++ks){
      #pragma unroll
      for (int k=0;k<8;k++){
        int c = lg*8 + ks*32 + k;
        const float* wt = &sWT[c*3];
        bf0[ks][k] = (short)f2bf(fmaxf(sZPb[c] + t0x*wt[0]+t0y*wt[1]+t0z*wt[2], 0.f));
      }
    }

    // dec2: full 128 output channels in one pass
    f32x4 acc[8];
    #pragma unroll
    for (int nf=0; nf<8; ++nf) acc[nf]=(f32x4)0.f;
    #pragma unroll
    for (int ks=0; ks<4; ++ks){
      #pragma unroll
      for (int nf=0; nf<8; ++nf){
        short8v a = *reinterpret_cast<const short8v*>(a2Base + nf*16*KP + ks*32);
        acc[nf] = __builtin_amdgcn_mfma_f32_16x16x32_bf16(a, bf0[ks], acc[nf], 0,0,0);
      }
    }
    #pragma unroll
    for (int nf=0; nf<8; ++nf){
      int c = nf*16 + lg*4;
      ushort4v o;
      #pragma unroll
      for (int reg=0; reg<4; ++reg)
        o[reg] = f2bf(fmaxf(acc[nf][reg] + sB2[c+reg], 0.f));
      *reinterpret_cast<ushort4v*>(&sH[(lrow + l15)*KP + c]) = o;
    }
    // no barrier: sH rows [lrow, lrow+16) are written and read only by this wave

    // dec3 (K=128 from wave-private sH)
    f32x4 acc3[4];
    #pragma unroll
    for (int nf=0; nf<4; ++nf) acc3[nf]=(f32x4)0.f;
    #pragma unroll
    for (int ks=0; ks<4; ++ks){
      short8v h0 = *reinterpret_cast<const short8v*>(&sH[(lrow + l15)*KP + ks*32 + lg*8]);
      #pragma unroll
      for (int nf=0; nf<4; ++nf){
        short8v a = *reinterpret_cast<const short8v*>(a3Base + nf*16*KP + ks*32);
        acc3[nf] = __builtin_amdgcn_mfma_f32_16x16x32_bf16(a, h0, acc3[nf], 0,0,0);
      }
    }

    // fused dec4 epilogue
    float p0 = 0.f, p1 = 0.f, p2 = 0.f;
    #pragma unroll
    for (int nf=0; nf<4; ++nf){
      #pragma unroll
      for (int reg=0; reg<4; ++reg){
        int c = nf*16 + lg*4 + reg;
        float h = fmaxf(acc3[nf][reg] + sB3[c], 0.f);
        p0 += h*sW4[c]; p1 += h*sW4[64+c]; p2 += h*sW4[128+c];
      }
    }
    p0 += __shfl_xor(p0,16); p0 += __shfl_xor(p0,32);
    p1 += __shfl_xor(p1,16); p1 += __shfl_xor(p1,32);
    p2 += __shfl_xor(p2,16); p2 += __shfl_xor(p2,32);
    if (lg == 0 && v0r < V){
      size_t o = ((size_t)b*V + v0r)*3;
      out[o+0] = tmpl[v0r*3+0] + p0 + sB4v[0];
      out[o+1] = tmpl[v0r*3+1] + p1 + sB4v[1];
      out[o+2] = tmpl[v0r*3+2] + p2 + sB4v[2];
    }
  }
}

extern "C" void kernel_launch(void* const* d_in, const int* in_sizes, int n_in,
                              void* d_out, int out_size, void* d_ws, size_t ws_size,
                              hipStream_t stream){
  const float* x    = (const float*)d_in[0];
  const float* eps  = (const float*)d_in[1];
  const int*   row  = (const int*)d_in[2];
  const int*   colx = (const int*)d_in[3];
  const float* vals = (const float*)d_in[4];
  const float* tmpl = (const float*)d_in[5];
  const float* W1 = (const float*)d_in[6];  const float* b1 = (const float*)d_in[7];
  const float* W2 = (const float*)d_in[8];  const float* b2 = (const float*)d_in[9];
  const float* W3 = (const float*)d_in[10]; const float* b3 = (const float*)d_in[11];
  const float* Wfc= (const float*)d_in[12]; const float* bfc= (const float*)d_in[13];
  const float* Wmu= (const float*)d_in[14]; const float* bmu= (const float*)d_in[15];
  const float* Wlv= (const float*)d_in[16]; const float* blv= (const float*)d_in[17];
  const float* Wd1= (const float*)d_in[18]; const float* bd1= (const float*)d_in[19];
  const float* Wd2= (const float*)d_in[20]; const float* bd2= (const float*)d_in[21];
  const float* Wd3= (const float*)d_in[22]; const float* bd3= (const float*)d_in[23];
  const float* Wd4= (const float*)d_in[24]; const float* bd4= (const float*)d_in[25];

  int V   = in_sizes[5] / 3;     // 10242
  int Bn  = in_sizes[1] / 32;    // 16
  int nnz = in_sizes[2];         // 71682
  int R   = Bn * V;              // 163872 (b-major rows: r = b*V + v)

  // workspace layout
  char* w = (char*)d_ws;
  size_t off = 0;
  auto alloc = [&](size_t bytes)->char*{
    char* p = w + off; off = (off + bytes + 255) & ~(size_t)255; return p;
  };
  unsigned short* bufA = (unsigned short*)alloc((size_t)R * 64 * 2);
  unsigned short* bufB = (unsigned short*)alloc((size_t)R * 64 * 2);
  int*   col8 = (int*)alloc((size_t)V*8*4);
  float* val8 = (float*)alloc((size_t)V*8*4);
  float* dvec = (float*)alloc((size_t)V*4);
  float* g    = (float*)alloc((size_t)Bn*128*4);
  float* zpb  = (float*)alloc((size_t)Bn*128*4);

  float* recon  = (float*)d_out;
  float* mu_out = recon + (size_t)R*3;
  float* lv_out = mu_out + (size_t)Bn*32;

  int NB1 = (V + 255) / 256;       // spmm_lin1: 256 rows/block
  int NB8 = (V*8 + 255) / 256;     // spmm8s: 32 rows/block
  int NTm = (V + 127) / 128;       // lin MFMA tiles (128 vertices)
  int NTd = (V + 63) / 64;         // dec tiles (64 vertices)
  int NBLK = 32;                   // blocks per batch for persistent-weight kernels

  // prep (col8/val8/dvec + zero g)
  prep_k<<<(V+255)/256, 256, 0, stream>>>(row, colx, vals, nnz, col8, val8, dvec, g, V, Bn*128);

  // encoder (all XCD-affine: batch b on XCD b%8)
  spmm_lin1_k<<<16*NB1, 256, 0, stream>>>(x, col8, val8, dvec, W1, b1, bufA, V, NB1);
  spmm8s_k<<<16*NB8, 256, 0, stream>>>(bufA, bufB, col8, val8, V, NB8);
  lin_mfma_k<64,64,true><<<16*NBLK, 256, 0, stream>>>(bufB, W2, b2, bufA, dvec, V, NBLK, NTm);
  spmm8s_k<<<16*NB8, 256, 0, stream>>>(bufA, bufB, col8, val8, V, NB8);
  lin3_mean_k<<<16*NBLK, 256, 0, stream>>>(bufB, W3, b3, dvec, g, V, NBLK, NTm);

  // head (feat/mu/lv/z/zpart)
  head2_k<<<Bn, 256, 0, stream>>>(g, Wfc, bfc, Wmu, bmu, Wlv, blv, eps, Wd1, bd1,
                                  mu_out, lv_out, zpb, 1.0f/(float)V);

  // full decoder: persistent weights, barrier-free tile loop
  dec_k<<<16*NBLK, 256, 0, stream>>>(zpb, tmpl, Wd1, Wd2, bd2, Wd3, bd3, Wd4, bd4,
                                     recon, V, NBLK, NTd);
}